// Round 7
// baseline (618.606 us; speedup 1.0000x reference)
//
#include <hip/hip_runtime.h>
#include <hip/hip_bf16.h>
#include <stdint.h>

// Problem dims (fixed by reference setup_inputs)
#define Mdim 8192   // B*S = 4*2048
#define Ndim 4096   // OUT
#define Kdim 4096   // IN

typedef int v4i __attribute__((ext_vector_type(4)));

// ---------------------------------------------------------------------------
// Kernel 1: quantize activations. xi = clip(rint((x*input_scale)*(1/act)))
// ---------------------------------------------------------------------------
__global__ void quant_x_kernel(const float* __restrict__ x,
                               const float* __restrict__ in_scale,
                               const float* __restrict__ act_scale_p,
                               int8_t* __restrict__ xq) {
  const float inv_act = 1.0f / (*act_scale_p);
  const int64_t tid = (int64_t)blockIdx.x * blockDim.x + threadIdx.x;
  const int64_t base = tid * 16;
  const int k0 = (int)(base & (Kdim - 1));  // Kdim is pow2
  const float4* xv = (const float4*)(x + base);
  const float4* sv = (const float4*)(in_scale + k0);
  alignas(16) int8_t ob[16];
#pragma unroll
  for (int j = 0; j < 4; ++j) {
    float4 xx = xv[j];
    float4 ss = sv[j];
    float r0 = rintf((xx.x * ss.x) * inv_act);
    float r1 = rintf((xx.y * ss.y) * inv_act);
    float r2 = rintf((xx.z * ss.z) * inv_act);
    float r3 = rintf((xx.w * ss.w) * inv_act);
    r0 = fminf(fmaxf(r0, -127.f), 127.f);
    r1 = fminf(fmaxf(r1, -127.f), 127.f);
    r2 = fminf(fmaxf(r2, -127.f), 127.f);
    r3 = fminf(fmaxf(r3, -127.f), 127.f);
    ob[j * 4 + 0] = (int8_t)r0;
    ob[j * 4 + 1] = (int8_t)r1;
    ob[j * 4 + 2] = (int8_t)r2;
    ob[j * 4 + 3] = (int8_t)r3;
  }
  *(v4i*)(xq + base) = *(const v4i*)ob;
}

// ---------------------------------------------------------------------------
// Kernel 2: pack int32 weights to int8 ([N,K] row-major kept as-is = B^T).
// ---------------------------------------------------------------------------
__global__ void pack_w_kernel(const int* __restrict__ w, int8_t* __restrict__ wq) {
  const int64_t tid = (int64_t)blockIdx.x * blockDim.x + threadIdx.x;
  const int64_t base = tid * 16;
  const int4* wv = (const int4*)(w + base);
  alignas(16) int8_t ob[16];
#pragma unroll
  for (int j = 0; j < 4; ++j) {
    int4 t = wv[j];
    ob[j * 4 + 0] = (int8_t)t.x;
    ob[j * 4 + 1] = (int8_t)t.y;
    ob[j * 4 + 2] = (int8_t)t.z;
    ob[j * 4 + 3] = (int8_t)t.w;
  }
  *(v4i*)(wq + base) = *(const v4i*)ob;
}

// ---------------------------------------------------------------------------
// Kernel 3: int8 GEMM, DIRECT-TO-REGISTER (no LDS). C = Aq[M,K] . Bq[N,K]^T
//
// R1-R6 post-mortems: every LDS-staged variant serializes the CU into
// {LDS-burst | MFMA-burst} (measured 5325 cyc/K-tile = 2611 MFMA + 2260
// ds_read + 512 DMA, exactly additive); 4 overlap schemes (compiler sched,
// raw barriers, reg pipeline, 2-block TLP) all failed — barriers/contention
// phase-lock the bursts. Fix: remove the LDS pipe from the critical path.
//
// Per CU per K-tile the UNIQUE operand bytes are A 32KB + B 32KB: L1-sized
// per slice (32KB), L2/L3-resident overall (Aq+Bq=48MB < 256MB L3). So load
// fragments directly global->VGPR at their natural (unswizzled) addresses:
// each load = 16 rows x 64B segments, L1/L2-served. Software-pipelined one
// K=64 slice ahead with two named register sets (static indexing, rule #20);
// compiler emits counted vmcnt(N) per set, loads drain under the 653-cyc
// MFMA clusters. No barriers -> waves free-run -> pipes overlap naturally.
//
// Budget per CU per K-tile: MFMA 2611 cyc; vector-mem <= 3072 line-cycles
// worst case (192 instr x 16 lines), L2 demand 24 B/cyc << 56 available.
// Registers: acc 128 + sets 96 + addr ~= 240 -> launch_bounds(512,2).
// Wave tile 128x64, block 256x256 (8 waves 2Mx4N), supertile mapping and
// epilogue identical to the verified R4 kernel.
// ---------------------------------------------------------------------------
__global__ __launch_bounds__(512, 2) void gemm_i8_kernel(
    const int8_t* __restrict__ Aq, const int8_t* __restrict__ Bq,
    const float* __restrict__ w_scale, const float* __restrict__ bias,
    const float* __restrict__ act_scale_p, float* __restrict__ out) {
  const int t = threadIdx.x;

  // Grid 512 = 32 m-blocks x 16 n-blocks; 2-wide m supertile for B reuse.
  const int lin = blockIdx.x;
  const int within = lin & 31;
  const int m_blk = (lin >> 5) * 2 + (within & 1);  // 0..31
  const int n_blk = within >> 1;                    // 0..15
  const int m0 = m_blk * 256;
  const int n0 = n_blk * 256;

  const int w = t >> 6;           // wave 0..7
  const int l = t & 63;           // lane
  const int wm = (w >> 2) * 128;  // wave C-rows origin within tile (2M)
  const int wn = (w & 3) * 64;    // wave C-cols origin within tile (4N)
  const int lrow = l & 15;        // fragment row (m for A, n for B)
  const int kch = (l >> 4) * 16;  // lane's k-chunk within K=64 (natural layout)

  // Fragment base addresses: frag f covers rows base + f*16; k advances +64.
  const int8_t* Ab = Aq + (int64_t)(m0 + wm + lrow) * Kdim + kch;
  const int8_t* Bb = Bq + (int64_t)(n0 + wn + lrow) * Kdim + kch;

  v4i acc[8][4] = {};
  v4i a0[8], b0[4], a1[8], b1[4];

#define LDA(dst, koff)                                                     \
  do {                                                                     \
    _Pragma("unroll") for (int i = 0; i < 8; ++i)                          \
        dst[i] = *(const v4i*)(Ab + (int64_t)i * (16 * Kdim) + (koff));    \
  } while (0)
#define LDB(dst, koff)                                                     \
  do {                                                                     \
    _Pragma("unroll") for (int j = 0; j < 4; ++j)                          \
        dst[j] = *(const v4i*)(Bb + (int64_t)j * (16 * Kdim) + (koff));    \
  } while (0)
#define MFMA32(AS, BS)                                                     \
  do {                                                                     \
    __builtin_amdgcn_s_setprio(1);                                         \
    _Pragma("unroll") for (int i = 0; i < 8; ++i) {                        \
      _Pragma("unroll") for (int j = 0; j < 4; ++j) {                      \
        acc[i][j] = __builtin_amdgcn_mfma_i32_16x16x64_i8(                 \
            AS[i], BS[j], acc[i][j], 0, 0, 0);                             \
      }                                                                    \
    }                                                                      \
    __builtin_amdgcn_s_setprio(0);                                         \
  } while (0)

  // Prime slice 0 into set 0.
  LDA(a0, 0);
  LDB(b0, 0);

  for (int ks = 0; ks < Kdim; ks += 128) {
    // Prefetch slice ks+64 into set 1, then compute set 0.
    LDA(a1, ks + 64);
    LDB(b1, ks + 64);
    MFMA32(a0, b0);

    // Prefetch slice ks+128 into set 0 (wrap to 0 on the last iter:
    // harmless re-read of slice 0, keeps addressing in-bounds), compute set 1.
    const int k2 = (ks + 128 < Kdim) ? (ks + 128) : 0;
    LDA(a0, k2);
    LDB(b0, k2);
    MFMA32(a1, b1);
  }

  // Epilogue: D mapping col = lane&15, row = (lane>>4)*4 + reg.
  // acc[f][j] covers rows m0+wm+f*16.., cols n0+wn+j*16.. (same as R4).
  const float act = *act_scale_p;
  const int rowbase = (l >> 4) * 4;
#pragma unroll
  for (int j = 0; j < 4; ++j) {
    const int n = n0 + wn + j * 16 + lrow;
    const float sc = act * w_scale[n];
    const float bs = bias[n];
#pragma unroll
    for (int i = 0; i < 8; ++i) {
      const int mb = m0 + wm + i * 16 + rowbase;
#pragma unroll
      for (int r = 0; r < 4; ++r) {
        out[(int64_t)(mb + r) * Ndim + n] = (float)acc[i][j][r] * sc + bs;
      }
    }
  }
}

// ---------------------------------------------------------------------------
extern "C" void kernel_launch(void* const* d_in, const int* in_sizes, int n_in,
                              void* d_out, int out_size, void* d_ws, size_t ws_size,
                              hipStream_t stream) {
  const float* x        = (const float*)d_in[0];
  const float* in_scale = (const float*)d_in[1];
  const float* actp     = (const float*)d_in[2];
  const int*   w_int    = (const int*)d_in[3];
  const float* w_scale  = (const float*)d_in[4];
  const float* bias     = (const float*)d_in[5];
  float* out = (float*)d_out;

  int8_t* Aq = (int8_t*)d_ws;                        // 32 MiB
  int8_t* Bq = (int8_t*)d_ws + (size_t)Mdim * Kdim;  // 16 MiB

  {
    const int64_t nthreads = (int64_t)Mdim * Kdim / 16;  // 2,097,152
    quant_x_kernel<<<(int)(nthreads / 256), 256, 0, stream>>>(x, in_scale, actp, Aq);
  }
  {
    const int64_t nthreads = (int64_t)Ndim * Kdim / 16;  // 1,048,576
    pack_w_kernel<<<(int)(nthreads / 256), 256, 0, stream>>>(w_int, Bq);
  }
  {
    gemm_i8_kernel<<<dim3(512), 512, 0, stream>>>(Aq, Bq, w_scale, bias, actp, out);
  }
}

// Round 8
// 398.374 us; speedup vs baseline: 1.5528x; 1.5528x over previous
//
#include <hip/hip_runtime.h>
#include <hip/hip_bf16.h>
#include <stdint.h>

// Problem dims (fixed by reference setup_inputs)
#define Mdim 8192   // B*S = 4*2048
#define Ndim 4096   // OUT
#define Kdim 4096   // IN

// GEMM tile geometry: 256x256 tile, BK=128 (two K=64 slices), 8 waves.
#define BM 256
#define BN 256
#define BK 128

typedef int v4i __attribute__((ext_vector_type(4)));

__device__ __forceinline__ void gload_lds16(const void* g, void* l) {
  __builtin_amdgcn_global_load_lds(
      (const __attribute__((address_space(1))) unsigned int*)g,
      (__attribute__((address_space(3))) unsigned int*)l,
      16 /*bytes*/, 0 /*offset*/, 0 /*aux*/);
}

// ---------------------------------------------------------------------------
// Kernel 1 (fused prep): quantize activations AND pack weights, one launch.
// Lane-contiguous accesses (4 passes/thread): each vector load = 1KB/wave
// contiguous (vs the old thread-contiguous 64B chunks that scattered each
// instruction across 64 cache lines); char4 stores = 256B/wave contiguous.
// Blocks 0..8191: one 4096-elem row of x each. Blocks 8192..12287: 4096
// int32 weights each. Same arithmetic/order as before -> bit-identical.
// ---------------------------------------------------------------------------
#define QBLOCKS 8192
__global__ __launch_bounds__(256) void prep_kernel(
    const float* __restrict__ x, const float* __restrict__ in_scale,
    const float* __restrict__ act_scale_p, const int* __restrict__ w,
    int8_t* __restrict__ xq, int8_t* __restrict__ wq) {
  const int b = blockIdx.x;
  const int t = threadIdx.x;
  if (b < QBLOCKS) {
    const float inv_act = 1.0f / (*act_scale_p);
    const int64_t rowbase = (int64_t)b * 4096;
#pragma unroll
    for (int p = 0; p < 4; ++p) {
      const int e = p * 1024 + t * 4;
      const float4 xx = *(const float4*)(x + rowbase + e);
      const float4 ss = *(const float4*)(in_scale + e);
      float r0 = rintf((xx.x * ss.x) * inv_act);
      float r1 = rintf((xx.y * ss.y) * inv_act);
      float r2 = rintf((xx.z * ss.z) * inv_act);
      float r3 = rintf((xx.w * ss.w) * inv_act);
      r0 = fminf(fmaxf(r0, -127.f), 127.f);
      r1 = fminf(fmaxf(r1, -127.f), 127.f);
      r2 = fminf(fmaxf(r2, -127.f), 127.f);
      r3 = fminf(fmaxf(r3, -127.f), 127.f);
      char4 o;
      o.x = (int8_t)r0; o.y = (int8_t)r1; o.z = (int8_t)r2; o.w = (int8_t)r3;
      *(char4*)(xq + rowbase + e) = o;
    }
  } else {
    const int64_t base = (int64_t)(b - QBLOCKS) * 4096;
#pragma unroll
    for (int p = 0; p < 4; ++p) {
      const int e = p * 1024 + t * 4;
      const int4 ww = *(const int4*)(w + base + e);
      char4 o;
      o.x = (int8_t)ww.x; o.y = (int8_t)ww.y; o.z = (int8_t)ww.z; o.w = (int8_t)ww.w;
      *(char4*)(wq + base + e) = o;
    }
  }
}

// ---------------------------------------------------------------------------
// Kernel 2: int8 GEMM — the verified R4 kernel, byte-for-byte (142 us best).
// 256^2 tile, 8 waves 2Mx4N, 4 phases/K-tile, raw pre-MFMA barrier (backend
// emits counted lgkm waits), counted VMCNT(4) at phases 1&3 only, XOR-
// swizzled 64B-row LDS via pre-swizzled global source (0 bank conflicts).
// ---------------------------------------------------------------------------
#define PBAR()                        \
  do {                                \
    asm volatile("" ::: "memory");    \
    __builtin_amdgcn_s_barrier();     \
    asm volatile("" ::: "memory");    \
  } while (0)
#define VMCNT(n) asm volatile("s_waitcnt vmcnt(" #n ")" ::: "memory")

#define MFMA16(mh)                                                        \
  do {                                                                    \
    __builtin_amdgcn_s_setprio(1);                                        \
    _Pragma("unroll") for (int i = 0; i < 4; ++i) {                       \
      _Pragma("unroll") for (int j = 0; j < 4; ++j) {                     \
        acc[(mh) * 4 + i][j] = __builtin_amdgcn_mfma_i32_16x16x64_i8(     \
            af[i], bf[j], acc[(mh) * 4 + i][j], 0, 0, 0);                 \
      }                                                                   \
    }                                                                     \
    __builtin_amdgcn_s_setprio(0);                                        \
  } while (0)

__global__ __launch_bounds__(512, 2) void gemm_i8_kernel(
    const int8_t* __restrict__ Aq, const int8_t* __restrict__ Bq,
    const float* __restrict__ w_scale, const float* __restrict__ bias,
    const float* __restrict__ act_scale_p, float* __restrict__ out) {
  __shared__ alignas(16) int8_t As[2][2][BM * 64];  // [buf][kslice] 4x16KB
  __shared__ alignas(16) int8_t Bs[2][2][BN * 64];

  const int t = threadIdx.x;

  // Grid 512 = 32 m-blocks x 16 n-blocks; 2-wide m supertile for B reuse.
  const int lin = blockIdx.x;
  const int within = lin & 31;
  const int m_blk = (lin >> 5) * 2 + (within & 1);  // 0..31
  const int n_blk = within >> 1;                    // 0..15
  const int m0 = m_blk * BM;
  const int n0 = n_blk * BN;

  // Staging: thread t fills LDS slot t*16 (row = t>>2 in half h, phys chunk
  // = (t&3) ^ ((row>>1)&3) applied to the GLOBAL source address).
  const int srow = t >> 2;                            // 0..127
  const int scol = ((t & 3) ^ ((t >> 3) & 3)) * 16;   // swizzled k-offset
  const int8_t* gA0 = Aq + (int64_t)(m0 + srow) * Kdim + scol;  // rows 0-127
  const int8_t* gA1 = gA0 + (int64_t)128 * Kdim;                // rows 128-255
  const int8_t* gB0 = Bq + (int64_t)(n0 + srow) * Kdim + scol;
  const int8_t* gB1 = gB0 + (int64_t)128 * Kdim;
  const int ldst = t * 16;

  const int w = t >> 6;           // wave 0..7
  const int l = t & 63;           // lane
  const int wm = (w >> 2) * 128;  // wave C-rows origin within tile (2M)
  const int wn = (w & 3) * 64;    // wave C-cols origin within tile (4N)
  const int lrow = l & 15;        // fragment row (m for A, n for B)
  const int lk = ((l >> 4) ^ ((l >> 1) & 3)) * 16;  // swizzled phys chunk
  const int abase = (wm + lrow) * 64 + lk;
  const int bbase = (wn + lrow) * 64 + lk;

  v4i acc[8][4] = {};

#define STG(MAT, buf, ks, h, koff) \
  gload_lds16(g##MAT##h + (koff) + (ks) * 64, &MAT##s[buf][ks][(h) * 8192 + ldst])

  // Prologue: stage tile 0 into buf 0 (order: ks0 h0, ks0 h1, ks1 h0, ks1 h1)
  STG(A, 0, 0, 0, 0); STG(B, 0, 0, 0, 0);
  STG(A, 0, 0, 1, 0); STG(B, 0, 0, 1, 0);
  STG(A, 0, 1, 0, 0); STG(B, 0, 1, 0, 0);
  STG(A, 0, 1, 1, 0); STG(B, 0, 1, 1, 0);
  VMCNT(4);  // k-slice 0 landed; slice 1's 4 loads stay in flight
  PBAR();

  for (int kt = 0; kt < Kdim; kt += BK) {
    const int cur = (kt >> 7) & 1;
    const int nxt = cur ^ 1;
    int kn = kt + BK;
    if (kn >= Kdim) kn = 0;  // dummy wrap: keeps vmcnt counts uniform

    v4i af[4], bf[4];

    // ---- phase 0: ks=0, mh=0 ----
#pragma unroll
    for (int j = 0; j < 4; ++j) bf[j] = *(const v4i*)&Bs[cur][0][bbase + j * 1024];
#pragma unroll
    for (int i = 0; i < 4; ++i) af[i] = *(const v4i*)&As[cur][0][abase + i * 1024];
    STG(A, nxt, 0, 0, kn); STG(B, nxt, 0, 0, kn);
    __builtin_amdgcn_s_barrier();  // raw: backend emits counted lgkm waits
    MFMA16(0);
    PBAR();

    // ---- phase 1: ks=0, mh=1 ----
#pragma unroll
    for (int i = 0; i < 4; ++i) af[i] = *(const v4i*)&As[cur][0][abase + 4096 + i * 1024];
    STG(A, nxt, 0, 1, kn); STG(B, nxt, 0, 1, kn);
    __builtin_amdgcn_s_barrier();
    MFMA16(1);
    VMCNT(4);  // drain this tile's k-slice 1; 4 prefetch loads in flight
    PBAR();

    // ---- phase 2: ks=1, mh=0 ----
#pragma unroll
    for (int j = 0; j < 4; ++j) bf[j] = *(const v4i*)&Bs[cur][1][bbase + j * 1024];
#pragma unroll
    for (int i = 0; i < 4; ++i) af[i] = *(const v4i*)&As[cur][1][abase + i * 1024];
    STG(A, nxt, 1, 0, kn); STG(B, nxt, 1, 0, kn);
    __builtin_amdgcn_s_barrier();
    MFMA16(0);
    PBAR();

    // ---- phase 3: ks=1, mh=1 ----
#pragma unroll
    for (int i = 0; i < 4; ++i) af[i] = *(const v4i*)&As[cur][1][abase + 4096 + i * 1024];
    STG(A, nxt, 1, 1, kn); STG(B, nxt, 1, 1, kn);
    __builtin_amdgcn_s_barrier();
    MFMA16(1);
    VMCNT(4);  // drain next tile's k-slice 0; its slice 1 stays in flight
    PBAR();
  }
  VMCNT(0);  // drain dummy prefetch before LDS teardown

  // Epilogue: D mapping col = lane&15, row = (lane>>4)*4 + reg
  const float act = *act_scale_p;
  const int rowbase = (l >> 4) * 4;
#pragma unroll
  for (int j = 0; j < 4; ++j) {
    const int n = n0 + wn + j * 16 + lrow;
    const float sc = act * w_scale[n];
    const float bs = bias[n];
#pragma unroll
    for (int i = 0; i < 8; ++i) {
      const int mb = m0 + wm + i * 16 + rowbase;
#pragma unroll
      for (int r = 0; r < 4; ++r) {
        out[(int64_t)(mb + r) * Ndim + n] = (float)acc[i][j][r] * sc + bs;
      }
    }
  }
}

// ---------------------------------------------------------------------------
extern "C" void kernel_launch(void* const* d_in, const int* in_sizes, int n_in,
                              void* d_out, int out_size, void* d_ws, size_t ws_size,
                              hipStream_t stream) {
  const float* x        = (const float*)d_in[0];
  const float* in_scale = (const float*)d_in[1];
  const float* actp     = (const float*)d_in[2];
  const int*   w_int    = (const int*)d_in[3];
  const float* w_scale  = (const float*)d_in[4];
  const float* bias     = (const float*)d_in[5];
  float* out = (float*)d_out;

  int8_t* Aq = (int8_t*)d_ws;                        // 32 MiB
  int8_t* Bq = (int8_t*)d_ws + (size_t)Mdim * Kdim;  // 16 MiB

  {
    // 8192 quant blocks + 4096 pack blocks, one launch.
    prep_kernel<<<dim3(12288), 256, 0, stream>>>(x, in_scale, actp, w_int, Aq, Bq);
  }
  {
    gemm_i8_kernel<<<dim3(512), 512, 0, stream>>>(Aq, Bq, w_scale, bias, actp, out);
  }
}